// Round 1
// baseline (73.584 us; speedup 1.0000x reference)
//
#include <hip/hip_runtime.h>
#include <math.h>

#define HH 512
#define WW 512
#define NB 8
#define NC 3
#define TILE 32
#define HW (HH*WW)

// K1: per-batch, per-32x32-tile: separable unnormalized Gaussian (9 tap, zero-pad)
// then Sobel (zero-pad of BLUR at image borders), sum over 3 channels:
// GM = sum_c sqrt(gx^2+gy^2)  (f64), sector k = rint((atan2(sgy,sgx)*180/pi+180)/45) & 7.
__global__ __launch_bounds__(256) void canny_gm_kernel(
    const float* __restrict__ img, const float* __restrict__ gwin,
    double* __restrict__ GM, unsigned char* __restrict__ KP)
{
    __shared__ float  simg[42][42];   // img tile, halo 5
    __shared__ double shb[42][34];    // horizontal gauss, cols tx0-1..tx0+32
    __shared__ double sbl[34][34];    // blur, rows/cols -1..+32

    const int tilesX = WW / TILE;
    const int tx0 = (blockIdx.x % tilesX) * TILE;
    const int ty0 = (blockIdx.x / tilesX) * TILE;
    const int b = blockIdx.y;
    const int t = threadIdx.x;

    double g[9];
#pragma unroll
    for (int k = 0; k < 9; ++k) g[k] = (double)gwin[k];

    double mag[4], sgx[4], sgy[4];
#pragma unroll
    for (int p = 0; p < 4; ++p) { mag[p] = 0.0; sgx[p] = 0.0; sgy[p] = 0.0; }

    for (int c = 0; c < NC; ++c) {
        const float* ip = img + ((size_t)b * NC + c) * HW;
        // load img tile with halo 5 (zero-pad outside image)
        for (int idx = t; idx < 42*42; idx += 256) {
            int r = idx / 42, col = idx % 42;
            int gr = ty0 - 5 + r, gc = tx0 - 5 + col;
            float v = 0.0f;
            if (gr >= 0 && gr < HH && gc >= 0 && gc < WW) v = ip[gr*WW + gc];
            simg[r][col] = v;
        }
        __syncthreads();
        // horizontal gauss: out col global = tx0-1+col; img col = tx0-5+col+k -> simg[r][col+k]
        for (int idx = t; idx < 42*34; idx += 256) {
            int r = idx / 34, col = idx % 34;
            double acc = 0.0;
#pragma unroll
            for (int k = 0; k < 9; ++k) acc += g[k] * (double)simg[r][col + k];
            shb[r][col] = acc;
        }
        __syncthreads();
        // vertical gauss: out row global = ty0-1+r; hb row = r+k
        for (int idx = t; idx < 34*34; idx += 256) {
            int r = idx / 34, col = idx % 34;
            double acc = 0.0;
#pragma unroll
            for (int k = 0; k < 9; ++k) acc += g[k] * shb[r + k][col];
            sbl[r][col] = acc;
        }
        __syncthreads();
        // sobel at the 32x32 tile (blur zero-padded at image borders)
#pragma unroll
        for (int p = 0; p < 4; ++p) {
            int pix = t + p * 256;
            int i = pix >> 5, j = pix & 31;
            int gi = ty0 + i, gj = tx0 + j;
            bool up = (gi - 1 >= 0), dn = (gi + 1 < HH), lf = (gj - 1 >= 0), rt = (gj + 1 < WW);
            double tl = (up && lf) ? sbl[i][j]     : 0.0;
            double tc = (up)       ? sbl[i][j+1]   : 0.0;
            double tr = (up && rt) ? sbl[i][j+2]   : 0.0;
            double ml = (lf)       ? sbl[i+1][j]   : 0.0;
            double mr = (rt)       ? sbl[i+1][j+2] : 0.0;
            double bl = (dn && lf) ? sbl[i+2][j]   : 0.0;
            double bc = (dn)       ? sbl[i+2][j+1] : 0.0;
            double br = (dn && rt) ? sbl[i+2][j+2] : 0.0;
            double gx = (tl - tr) + 2.0*(ml - mr) + (bl - br);
            double gy = (tl + 2.0*tc + tr) - (bl + 2.0*bc + br);
            mag[p] += sqrt(gx*gx + gy*gy);
            sgx[p] += gx; sgy[p] += gy;
        }
        __syncthreads();  // protect simg/shb/sbl before next channel
    }

#pragma unroll
    for (int p = 0; p < 4; ++p) {
        int pix = t + p * 256;
        int i = pix >> 5, j = pix & 31;
        int gi = ty0 + i, gj = tx0 + j;
        size_t o = (size_t)b * HW + (size_t)gi * WW + gj;
        GM[o] = mag[p];
        double ori = atan2(sgy[p], sgx[p]) * (180.0 / M_PI) + 180.0;
        int k = (int)rint(ori / 45.0);   // 0..8, round-half-even like jnp.round
        KP[o] = (unsigned char)(k & 7);  // k_pos = k % 8
    }
}

// K2: faithful replication of the flat gather (batch<->direction swap):
// pos(b,i,j) = GM[kp,i,j] - GM[kp, i+dr(b), j+dc(b)] (0 if neighbor OOB)
// neg uses kn = (kp+4)&7, same offset. thin = min(pos,neg)>0 ? GM[b,i,j] : 0.
// code bit0: thin > 0.3 ; bit1: 0.1 <= thin <= 0.3
__global__ __launch_bounds__(256) void canny_thin_kernel(
    const double* __restrict__ GM, const unsigned char* __restrict__ KP,
    unsigned char* __restrict__ CODE)
{
    int idx = blockIdx.x * blockDim.x + threadIdx.x;
    if (idx >= NB * HW) return;
    int j = idx & (WW - 1);
    int i = (idx >> 9) & (HH - 1);
    int b = idx >> 18;

    const int drt[8] = {0, 1, 1, 1, 0, -1, -1, -1};
    const int dct[8] = {1, 1, 0, -1, -1, -1, 0, 1};

    int kp = KP[idx];
    int kn = (kp + 4) & 7;
    int ni = i + drt[b], nj = j + dct[b];
    bool nin = (ni >= 0 && ni < HH && nj >= 0 && nj < WW);
    size_t p0 = (size_t)i * WW + j;
    size_t pn = (size_t)ni * WW + nj;

    double gmp  = GM[(size_t)kp * HW + p0];
    double gmn  = GM[(size_t)kn * HW + p0];
    double gmpn = nin ? GM[(size_t)kp * HW + pn] : 0.0;
    double gmnn = nin ? GM[(size_t)kn * HW + pn] : 0.0;

    double pos = gmp - gmpn;
    double neg = gmn - gmnn;
    double thin = (fmin(pos, neg) > 0.0) ? GM[idx] : 0.0;

    unsigned char code = 0;
    if (thin > 0.3) code |= 1;
    if (thin >= 0.1 && thin <= 0.3) code |= 2;
    CODE[idx] = code;
}

// K3: out = !border && (higher || (middle && any 8-neighbor higher))
__global__ __launch_bounds__(256) void canny_out_kernel(
    const unsigned char* __restrict__ CODE, float* __restrict__ out)
{
    int idx = blockIdx.x * blockDim.x + threadIdx.x;
    if (idx >= NB * HW) return;
    int j = idx & (WW - 1);
    int i = (idx >> 9) & (HH - 1);
    int b = idx >> 18;

    float r = 0.0f;
    if (i > 0 && i < HH - 1 && j > 0 && j < WW - 1) {
        unsigned char c = CODE[idx];
        if (c & 1) {
            r = 1.0f;
        } else if (c & 2) {
            const unsigned char* base = CODE + (size_t)b * HW;
            int any = 0;
            // all 8 neighbors are in-bounds for non-border pixels
            any |= base[(size_t)(i-1)*WW + (j-1)] & 1;
            any |= base[(size_t)(i-1)*WW + (j  )] & 1;
            any |= base[(size_t)(i-1)*WW + (j+1)] & 1;
            any |= base[(size_t)(i  )*WW + (j-1)] & 1;
            any |= base[(size_t)(i  )*WW + (j+1)] & 1;
            any |= base[(size_t)(i+1)*WW + (j-1)] & 1;
            any |= base[(size_t)(i+1)*WW + (j  )] & 1;
            any |= base[(size_t)(i+1)*WW + (j+1)] & 1;
            if (any) r = 1.0f;
        }
    }
    out[idx] = r;
}

extern "C" void kernel_launch(void* const* d_in, const int* in_sizes, int n_in,
                              void* d_out, int out_size, void* d_ws, size_t ws_size,
                              hipStream_t stream) {
    const float* img  = (const float*)d_in[0];
    const float* gwin = (const float*)d_in[1];   // gauss window, 9 f32

    // workspace layout: GM f64 [8*512*512] (16MB) | KP u8 (2MB) | CODE u8 (2MB)
    double* GM = (double*)d_ws;
    unsigned char* KP = (unsigned char*)d_ws + (size_t)NB * HW * sizeof(double);
    unsigned char* CODE = KP + (size_t)NB * HW;
    float* out = (float*)d_out;

    dim3 g1((HH / TILE) * (WW / TILE), NB);
    canny_gm_kernel<<<g1, 256, 0, stream>>>(img, gwin, GM, KP);

    int nblk = (NB * HW) / 256;
    canny_thin_kernel<<<nblk, 256, 0, stream>>>(GM, KP, CODE);
    canny_out_kernel<<<nblk, 256, 0, stream>>>(CODE, out);
}